// Round 3
// baseline (6579.022 us; speedup 1.0000x reference)
//
#include <hip/hip_runtime.h>
#include <stdint.h>

typedef unsigned short u16;
typedef unsigned int u32;
typedef unsigned long long u64;
typedef __attribute__((ext_vector_type(8))) short bf16x8;
typedef __attribute__((ext_vector_type(4))) float f32x4;
typedef __attribute__((ext_vector_type(4))) u32 u32x4;

#define T_STEPS 256
#define BATCH 64
#define NBLK 256
#define THREADS 512
#define KPAD 2056       // padded K stride (bf16 elems) for LDS W
#define CSTR 18         // cand stride (f32) -> 2-way banks only (free)
#define CNT_STRIDE 128  // u32 per barrier id (8 slots x 64B)
#define GO_OFF 0x22000
#define H_OFF 0x80000
#define HSLOT 65536     // elems per h step-slot (64x1024 bf16 = 128 KB)
#define LDS_W 65792
#define LDS_CAND (256 * CSTR * 4)
#define LDS_BYTES (LDS_W + LDS_CAND + 512)

static __device__ __forceinline__ u16 f2bf(float f) {  // RNE
  u32 u = __builtin_bit_cast(u32, f);
  u += 0x7FFFu + ((u >> 16) & 1u);
  return (u16)(u >> 16);
}
// round-half-up bf16 pack of 2 floats via v_perm (3 inst / 2 elems)
static __device__ __forceinline__ u32 pkbf(float lo, float hi) {
  u32 a = __builtin_bit_cast(u32, lo) + 0x8000u;
  u32 b = __builtin_bit_cast(u32, hi) + 0x8000u;
  return __builtin_amdgcn_perm(b, a, 0x07060302);  // {b[3],b[2],a[3],a[2]}
}
static __device__ __forceinline__ bf16x8 cvt8(f32x4 p, f32x4 q) {
  u32x4 r;
  r[0] = pkbf(p[0], p[1]); r[1] = pkbf(p[2], p[3]);
  r[2] = pkbf(q[0], q[1]); r[3] = pkbf(q[2], q[3]);
  return __builtin_bit_cast(bf16x8, r);
}
static __device__ __forceinline__ float sigf(float x) {
  return __builtin_amdgcn_rcpf(1.f + __expf(-x));
}
static __device__ __forceinline__ float tanhf_(float x) {
  float ax = __builtin_fabsf(x);
  float e = __expf(-2.f * ax);
  float t = 1.f - 2.f * e * __builtin_amdgcn_rcpf(1.f + e);
  return __builtin_copysignf(t, x);
}

// One-time heavy barrier (bar id 256): normal cached stores precede it, so
// release = threadfence (wbl2) before arrive, acquire = threadfence (inv).
static __device__ __forceinline__ void gbar_heavy(u32* cnt, u32* go, int bid,
                                                  int tid) {
  __syncthreads();
  if (tid == 0) {
    __threadfence();
    __hip_atomic_fetch_add(&cnt[256 * CNT_STRIDE + (bid & 7) * 16], 1u,
                           __ATOMIC_RELAXED, __HIP_MEMORY_SCOPE_AGENT);
  }
  if (bid == 0) {
    if (tid < 8) {
      while (__hip_atomic_load(&cnt[256 * CNT_STRIDE + tid * 16],
                               __ATOMIC_RELAXED, __HIP_MEMORY_SCOPE_AGENT) <
             (u32)(NBLK / 8))
        __builtin_amdgcn_s_sleep(1);
      __hip_atomic_store(&go[256 * CNT_STRIDE + tid * 16], 1u, __ATOMIC_RELAXED,
                         __HIP_MEMORY_SCOPE_AGENT);
    }
  } else if (tid == 0) {
    while (__hip_atomic_load(&go[256 * CNT_STRIDE + (bid & 7) * 16],
                             __ATOMIC_RELAXED, __HIP_MEMORY_SCOPE_AGENT) == 0u)
      __builtin_amdgcn_s_sleep(2);
  }
  if (tid == 0) __threadfence();
  __syncthreads();
}

__global__ __launch_bounds__(THREADS, 2)
void lstm_persistent(const float* __restrict__ x, const float* __restrict__ h0,
                     const float* __restrict__ c0, const float* __restrict__ W,
                     const float* __restrict__ bias, const int* __restrict__ L,
                     float* __restrict__ out, u16* __restrict__ hbuf,
                     u32* __restrict__ cnt, u32* __restrict__ go) {
  extern __shared__ char smem[];
  u16* Wlds = (u16*)smem;                    // [16 cols][KPAD] bf16
  float* cand = (float*)(smem + LDS_W);      // [256 rows][CSTR] f32
  u16* hstage = (u16*)(smem + LDS_W + LDS_CAND);  // [256] bf16

  const int bid = blockIdx.x;
  const int tid = threadIdx.x;
  const int wave = tid >> 6;
  const int lane = tid & 63;
  const int q = lane >> 4;
  const int ln = lane & 15;
  const int mh = wave & 1;   // M half
  const int kh = wave >> 1;  // K quarter
  const bool isx = (kh < 2);

  // ---- phase 0a: h0 -> bf16 into step-slot 0 ----
  {
    const int gtid = bid * THREADS + tid;
    if (gtid < BATCH * 1024) hbuf[gtid] = f2bf(h0[gtid]);
  }
  // ---- phase 0b: W slice -> LDS (bf16, column-major, K-padded) ----
  {
    const int g = tid & 3;
    const int kq2 = tid >> 2;
    const f32x4* Wv = (const f32x4*)W;  // one W row = 1024 f32x4
#pragma unroll 4
    for (int i = 0; i < 16; ++i) {
      int k = kq2 + 128 * i;
      f32x4 w4 = Wv[(size_t)k * 1024 + g * 256 + bid];
#pragma unroll
      for (int jj = 0; jj < 4; ++jj)
        Wlds[(g * 4 + jj) * KPAD + k] = f2bf(w4[jj]);
    }
  }

  // ---- per-thread pointwise state ----
  float c_reg = 0.f, h_reg = 0.f, b_i = 0.f, b_f = 0.f, b_o = 0.f, b_g = 0.f;
  int Lb = 0, pb = 0, pj = 0;
  if (tid < 256) {
    pb = tid >> 2;
    pj = tid & 3;
    int gj = bid * 4 + pj;
    Lb = L[pb];
    c_reg = c0[pb * 1024 + gj];
    h_reg = h0[pb * 1024 + gj];
    b_i = bias[0 * 1024 + gj];
    b_f = bias[1 * 1024 + gj];
    b_o = bias[2 * 1024 + gj];
    b_g = bias[3 * 1024 + gj];
  }

  gbar_heavy(cnt, go, bid, tid);  // h0/W visible everywhere

  // ---- hoist W fragments into registers for all 256 steps ----
  const int arow = 32 * mh + ln;
  bf16x8 Wf[16];
  {
    const u16* wp = &Wlds[ln * KPAD + kh * 512 + q * 8];
#pragma unroll
    for (int ks = 0; ks < 16; ++ks) Wf[ks] = *(const bf16x8*)(wp + ks * 32);
  }

  for (int t = 0; t < T_STEPS; ++t) {
    f32x4 acc0 = {0.f, 0.f, 0.f, 0.f};
    f32x4 acc1 = {0.f, 0.f, 0.f, 0.f};
    if (isx) {
      // ---- x-GEMM (no dependency on h(t)) — runs under barrier latency ----
      const float* px0 = x + (size_t)t * 65536 + arow * 1024 + kh * 512 + q * 8;
      const float* px1 = px0 + 16 * 1024;
      f32x4 F[4][4];  // rolling chunk: 4 ks x {t0.lo,t0.hi,t1.lo,t1.hi}
      bf16x8 Xa[4], Xb[4];
#pragma unroll
      for (int ks = 0; ks < 4; ++ks) {
        F[ks][0] = *(const f32x4*)(px0 + ks * 32);
        F[ks][1] = *(const f32x4*)(px0 + ks * 32 + 4);
        F[ks][2] = *(const f32x4*)(px1 + ks * 32);
        F[ks][3] = *(const f32x4*)(px1 + ks * 32 + 4);
      }
#pragma unroll
      for (int c = 0; c < 4; ++c) {
#pragma unroll
        for (int ks = 0; ks < 4; ++ks) {
          Xa[ks] = cvt8(F[ks][0], F[ks][1]);
          Xb[ks] = cvt8(F[ks][2], F[ks][3]);
        }
        if (c < 3) {
#pragma unroll
          for (int ks = 0; ks < 4; ++ks) {
            int kk = (c + 1) * 4 + ks;
            F[ks][0] = *(const f32x4*)(px0 + kk * 32);
            F[ks][1] = *(const f32x4*)(px0 + kk * 32 + 4);
            F[ks][2] = *(const f32x4*)(px1 + kk * 32);
            F[ks][3] = *(const f32x4*)(px1 + kk * 32 + 4);
          }
        }
#pragma unroll
        for (int ks = 0; ks < 4; ++ks) {
          acc0 = __builtin_amdgcn_mfma_f32_16x16x32_bf16(Xa[ks], Wf[c * 4 + ks],
                                                         acc0, 0, 0, 0);
          acc1 = __builtin_amdgcn_mfma_f32_16x16x32_bf16(Xb[ks], Wf[c * 4 + ks],
                                                         acc1, 0, 0, 0);
        }
      }
      // write partials (rows 0..127); pointwise(t-1) finished before loop top
      float* c0p = &cand[(kh * 64 + 32 * mh + q * 4) * CSTR + ln];
      float* c1p = c0p + 16 * CSTR;
#pragma unroll
      for (int r = 0; r < 4; ++r) {
        c0p[r * CSTR] = acc0[r];
        c1p[r * CSTR] = acc1[r];
      }
    }
    // ---- wait for h step-slot t (published at end of iter t-1) ----
    if (t > 0) {
      if (bid == 0) {
        if (tid < 8) {
          while (__hip_atomic_load(&cnt[(t - 1) * CNT_STRIDE + tid * 16],
                                   __ATOMIC_RELAXED,
                                   __HIP_MEMORY_SCOPE_AGENT) < (u32)(NBLK / 8))
            __builtin_amdgcn_s_sleep(1);
          // wave reconverges only when all 8 counters full -> safe to go
          __hip_atomic_store(&go[(t - 1) * CNT_STRIDE + tid * 16], 1u,
                             __ATOMIC_RELAXED, __HIP_MEMORY_SCOPE_AGENT);
        }
      } else if (tid == 0) {
        while (__hip_atomic_load(&go[(t - 1) * CNT_STRIDE + (bid & 7) * 16],
                                 __ATOMIC_RELAXED,
                                 __HIP_MEMORY_SCOPE_AGENT) == 0u)
          __builtin_amdgcn_s_sleep(2);
      }
      __syncthreads();
    }
    if (!isx) {
      // ---- h-GEMM: normal cached loads from fresh step-slot t ----
      const u16* ph0 =
          hbuf + (size_t)t * HSLOT + arow * 1024 + (kh - 2) * 512 + q * 8;
      const u16* ph1 = ph0 + 16 * 1024;
      bf16x8 A0[16], A1[16];
#pragma unroll
      for (int ks = 0; ks < 16; ++ks) {
        A0[ks] = *(const bf16x8*)(ph0 + ks * 32);
        A1[ks] = *(const bf16x8*)(ph1 + ks * 32);
      }
#pragma unroll
      for (int ks = 0; ks < 16; ++ks) {
        acc0 = __builtin_amdgcn_mfma_f32_16x16x32_bf16(A0[ks], Wf[ks], acc0, 0,
                                                       0, 0);
        acc1 = __builtin_amdgcn_mfma_f32_16x16x32_bf16(A1[ks], Wf[ks], acc1, 0,
                                                       0, 0);
      }
      float* c0p = &cand[(kh * 64 + 32 * mh + q * 4) * CSTR + ln];
      float* c1p = c0p + 16 * CSTR;
#pragma unroll
      for (int r = 0; r < 4; ++r) {
        c0p[r * CSTR] = acc0[r];
        c1p[r * CSTR] = acc1[r];
      }
    }
    __syncthreads();
    // ---- pointwise: reduce 4 K-quarters, gates, state update ----
    if (tid < 256) {
      float vi = b_i, vf = b_f, vo = b_o, vg = b_g;
#pragma unroll
      for (int p = 0; p < 4; ++p) {
        const float* cp = &cand[(p * 64 + pb) * CSTR];
        vi += cp[pj];
        vf += cp[4 + pj];
        vo += cp[8 + pj];
        vg += cp[12 + pj];
      }
      float ig = sigf(vi), fg = sigf(vf), og = sigf(vo), gg = tanhf_(vg);
      float cn = ig * gg + fg * c_reg;
      float hn = og * tanhf_(cn);
      if (t < Lb) { c_reg = cn; h_reg = hn; }
      out[((size_t)t * BATCH + pb) * 1024 + bid * 4 + pj] = h_reg;
      hstage[tid] = f2bf(h_reg);
    }
    __syncthreads();
    if (tid < 64) {
      // publish h(t) into fresh step-slot t+1 (sc1 -> IF$, device-visible)
      u64 v = ((const u64*)hstage)[tid];
      u64* dst = (u64*)(hbuf + (size_t)(t + 1) * HSLOT + tid * 1024 + bid * 4);
      __hip_atomic_store(dst, v, __ATOMIC_RELAXED, __HIP_MEMORY_SCOPE_AGENT);
    }
    __syncthreads();  // drain publishes (vmcnt(0) before s_barrier)
    if (tid == 0)
      __hip_atomic_fetch_add(&cnt[t * CNT_STRIDE + (bid & 7) * 16], 1u,
                             __ATOMIC_RELAXED, __HIP_MEMORY_SCOPE_AGENT);
  }
}

extern "C" void kernel_launch(void* const* d_in, const int* in_sizes, int n_in,
                              void* d_out, int out_size, void* d_ws, size_t ws_size,
                              hipStream_t stream) {
  (void)in_sizes; (void)n_in; (void)out_size; (void)ws_size;
  const float* x = (const float*)d_in[0];
  const float* h0 = (const float*)d_in[1];
  const float* c0 = (const float*)d_in[2];
  const float* W = (const float*)d_in[3];
  const float* bias = (const float*)d_in[4];
  const int* L = (const int*)d_in[5];
  float* out = (float*)d_out;

  char* ws = (char*)d_ws;
  u32* cnt = (u32*)ws;
  u32* go = (u32*)(ws + GO_OFF);
  u16* hbuf = (u16*)(ws + H_OFF);

  hipFuncSetAttribute(reinterpret_cast<const void*>(lstm_persistent),
                      hipFuncAttributeMaxDynamicSharedMemorySize, 160 * 1024);
  hipMemsetAsync(ws, 0, H_OFF, stream);  // zero cnt + go
  hipLaunchKernelGGL(lstm_persistent, dim3(NBLK), dim3(THREADS), LDS_BYTES,
                     stream, x, h0, c0, W, bias, L, out, hbuf, cnt, go);
}

// Round 4
// 4189.659 us; speedup vs baseline: 1.5703x; 1.5703x over previous
//
#include <hip/hip_runtime.h>
#include <stdint.h>

typedef unsigned short u16;
typedef unsigned int u32;
typedef unsigned long long u64;
typedef __attribute__((ext_vector_type(8))) short bf16x8;
typedef __attribute__((ext_vector_type(4))) float f32x4;
typedef __attribute__((ext_vector_type(4))) u16 u16x4;

#define T_STEPS 256
#define BATCH 64
#define NBLK 256
#define THREADS 576     // waves 0-7: GEMM; wave 8: dedicated sync wave
#define KPAD 2056       // padded K stride (bf16 elems) for LDS W
#define CSTR 18         // cand stride (f32): 2-way banks only (free)
#define CNT_STRIDE 128  // u32 per barrier id (8 slots x 64B)
#define GO_OFF 0x22000
#define X_OFF 0x80000                      // xbf: 256*64*1024 bf16 = 32 MiB
#define H_OFF (X_OFF + 0x2000000)          // hbuf: 257 step-slots x 128 KiB
#define HSLOT 65536                        // elems per h step-slot
#define LDS_W 65792
#define LDS_CAND (256 * CSTR * 4)
#define LDS_BYTES (LDS_W + LDS_CAND + 512) // 84736 B -> 1 block/CU (no deadlock)

static __device__ __forceinline__ u16 f2bf(float f) {  // RNE
  u32 u = __builtin_bit_cast(u32, f);
  u += 0x7FFFu + ((u >> 16) & 1u);
  return (u16)(u >> 16);
}
static __device__ __forceinline__ float sigf(float x) {
  return __builtin_amdgcn_rcpf(1.f + __expf(-x));
}
static __device__ __forceinline__ float tanhf_(float x) {
  float ax = __builtin_fabsf(x);
  float e = __expf(-2.f * ax);
  float t = 1.f - 2.f * e * __builtin_amdgcn_rcpf(1.f + e);
  return __builtin_copysignf(t, x);
}

// One-time heavy barrier: normal cached stores precede it, so release =
// threadfence (wbl2) before arrive; acquire = threadfence (inv) after — the
// inv on every block also flushes harness-poison (0xAA) lines from all L2s,
// which is what makes later cached reads of fresh step-slots safe.
static __device__ __forceinline__ void gbar_heavy(u32* cnt, u32* go, int bid,
                                                  int tid) {
  __syncthreads();
  if (tid == 0) {
    __threadfence();
    __hip_atomic_fetch_add(&cnt[256 * CNT_STRIDE + (bid & 7) * 16], 1u,
                           __ATOMIC_RELAXED, __HIP_MEMORY_SCOPE_AGENT);
  }
  if (bid == 0) {
    if (tid < 8) {
      while (__hip_atomic_load(&cnt[256 * CNT_STRIDE + tid * 16],
                               __ATOMIC_RELAXED, __HIP_MEMORY_SCOPE_AGENT) <
             (u32)(NBLK / 8))
        __builtin_amdgcn_s_sleep(1);
      __hip_atomic_store(&go[256 * CNT_STRIDE + tid * 16], 1u, __ATOMIC_RELAXED,
                         __HIP_MEMORY_SCOPE_AGENT);
    }
  } else if (tid == 0) {
    while (__hip_atomic_load(&go[256 * CNT_STRIDE + (bid & 7) * 16],
                             __ATOMIC_RELAXED, __HIP_MEMORY_SCOPE_AGENT) == 0u)
      __builtin_amdgcn_s_sleep(2);
  }
  if (tid == 0) __threadfence();
  __syncthreads();
}

__global__ __launch_bounds__(THREADS)
void lstm_persistent(const float* __restrict__ x, const float* __restrict__ h0,
                     const float* __restrict__ c0, const float* __restrict__ W,
                     const float* __restrict__ bias, const int* __restrict__ L,
                     float* __restrict__ out, u16* __restrict__ xbf,
                     u16* __restrict__ hbuf, u32* __restrict__ cnt,
                     u32* __restrict__ go) {
  extern __shared__ char smem[];
  u16* Wlds = (u16*)smem;                         // [16 cols][KPAD] bf16
  float* cand = (float*)(smem + LDS_W);           // [256 rows][CSTR] f32
  u16* hstage = (u16*)(smem + LDS_W + LDS_CAND);  // [256] bf16

  const int bid = blockIdx.x;
  const int tid = threadIdx.x;
  const int wv = tid >> 6;   // 0..8
  const int lane = tid & 63;
  const int q = lane >> 4;
  const int ln = lane & 15;
  const int mh = wv & 1;          // M half (waves 0-7)
  const int kh = (wv >> 1) & 3;   // K quarter (waves 0-7)
  const bool gemmw = (wv < 8);
  const bool isx = gemmw && (kh < 2);
  const bool ish = gemmw && (kh >= 2);

  // ---- phase 0a: x -> bf16 (grid-wide), h0 -> bf16 into step-slot 0 ----
  if (tid < 512) {
    const int gtid = bid * 512 + tid;
    const f32x4* xv = (const f32x4*)x;
    u16x4* ov = (u16x4*)xbf;
#pragma unroll
    for (int it = 0; it < 32; ++it) {
      int i = gtid + it * (NBLK * 512);
      f32x4 v = xv[i];
      u16x4 o;
      o[0] = f2bf(v[0]); o[1] = f2bf(v[1]); o[2] = f2bf(v[2]); o[3] = f2bf(v[3]);
      ov[i] = o;
    }
    if (gtid < BATCH * 1024) hbuf[gtid] = f2bf(h0[gtid]);
  }
  // ---- phase 0b: W slice -> LDS (bf16, column-major, K-padded) ----
  if (tid < 512) {
    const int g = tid & 3;
    const int kq2 = tid >> 2;  // 0..127
    const f32x4* Wv = (const f32x4*)W;  // one W row = 1024 f32x4
#pragma unroll 4
    for (int i = 0; i < 16; ++i) {
      int k = kq2 + 128 * i;
      f32x4 w4 = Wv[(size_t)k * 1024 + g * 256 + bid];
#pragma unroll
      for (int jj = 0; jj < 4; ++jj)
        Wlds[(g * 4 + jj) * KPAD + k] = f2bf(w4[jj]);
    }
  }

  // ---- per-thread pointwise state (threads 0..255 = waves 0-3) ----
  float c_reg = 0.f, h_reg = 0.f, b_i = 0.f, b_f = 0.f, b_o = 0.f, b_g = 0.f;
  int Lb = 0, pb = 0, pj = 0;
  if (tid < 256) {
    pb = tid >> 2;
    pj = tid & 3;
    int gj = bid * 4 + pj;
    Lb = L[pb];
    c_reg = c0[pb * 1024 + gj];
    h_reg = h0[pb * 1024 + gj];
    b_i = bias[0 * 1024 + gj];
    b_f = bias[1 * 1024 + gj];
    b_o = bias[2 * 1024 + gj];
    b_g = bias[3 * 1024 + gj];
  }

  gbar_heavy(cnt, go, bid, tid);  // xbf/h0/W visible; all L2s invalidated

  // ---- hoist this wave's W fragments into registers (all 256 steps) ----
  const int arow = 32 * mh + ln;
  bf16x8 Wf[16];
  if (gemmw) {
    const u16* wp = &Wlds[ln * KPAD + kh * 512 + q * 8];
#pragma unroll
    for (int ks = 0; ks < 16; ++ks) Wf[ks] = *(const bf16x8*)(wp + ks * 32);
  }

  for (int t = 0; t < T_STEPS; ++t) {
    f32x4 acc0 = {0.f, 0.f, 0.f, 0.f};
    f32x4 acc1 = {0.f, 0.f, 0.f, 0.f};
    if (isx) {
      // ---- x-GEMM: runs under barrier-propagation shadow ----
      const u16* p0 = xbf + (size_t)t * 65536 + arow * 1024 + kh * 512 + q * 8;
      bf16x8 A0[16], A1[16];
#pragma unroll
      for (int ks = 0; ks < 16; ++ks) {
        A0[ks] = *(const bf16x8*)(p0 + ks * 32);
        A1[ks] = *(const bf16x8*)(p0 + 16 * 1024 + ks * 32);
      }
      __builtin_amdgcn_sched_barrier(0);  // all 32 loads issued before use
#pragma unroll
      for (int ks = 0; ks < 16; ++ks) {
        acc0 = __builtin_amdgcn_mfma_f32_16x16x32_bf16(A0[ks], Wf[ks], acc0, 0, 0, 0);
        acc1 = __builtin_amdgcn_mfma_f32_16x16x32_bf16(A1[ks], Wf[ks], acc1, 0, 0, 0);
      }
      float* c0p = &cand[(kh * 64 + 32 * mh + q * 4) * CSTR + ln];
      float* c1p = c0p + 16 * CSTR;
#pragma unroll
      for (int r = 0; r < 4; ++r) {
        c0p[r * CSTR] = acc0[r];
        c1p[r * CSTR] = acc1[r];
      }
    } else if (wv == 8 && t > 0) {
      // ---- dedicated sync wave: never blocked by GEMM work ----
      if (bid == 0) {
        if (lane < 8) {
          while (__hip_atomic_load(&cnt[(t - 1) * CNT_STRIDE + lane * 16],
                                   __ATOMIC_RELAXED,
                                   __HIP_MEMORY_SCOPE_AGENT) < (u32)(NBLK / 8))
            __builtin_amdgcn_s_sleep(1);
          __hip_atomic_store(&go[(t - 1) * CNT_STRIDE + lane * 16], 1u,
                             __ATOMIC_RELAXED, __HIP_MEMORY_SCOPE_AGENT);
        }
      } else if (lane == 0) {
        while (__hip_atomic_load(&go[(t - 1) * CNT_STRIDE + (bid & 7) * 16],
                                 __ATOMIC_RELAXED,
                                 __HIP_MEMORY_SCOPE_AGENT) == 0u)
          __builtin_amdgcn_s_sleep(1);
      }
    }
    __syncthreads();  // go(t-1) observed -> h step-slot t is published
    if (ish) {
      // ---- h-GEMM: cached loads from fresh step-slot t (L2 broadcast) ----
      const u16* p0 =
          hbuf + (size_t)t * HSLOT + arow * 1024 + (kh - 2) * 512 + q * 8;
      bf16x8 A0[16], A1[16];
#pragma unroll
      for (int ks = 0; ks < 16; ++ks) {
        A0[ks] = *(const bf16x8*)(p0 + ks * 32);
        A1[ks] = *(const bf16x8*)(p0 + 16 * 1024 + ks * 32);
      }
      __builtin_amdgcn_sched_barrier(0);  // full 32-deep MLP before first wait
#pragma unroll
      for (int ks = 0; ks < 16; ++ks) {
        acc0 = __builtin_amdgcn_mfma_f32_16x16x32_bf16(A0[ks], Wf[ks], acc0, 0, 0, 0);
        acc1 = __builtin_amdgcn_mfma_f32_16x16x32_bf16(A1[ks], Wf[ks], acc1, 0, 0, 0);
      }
      float* c0p = &cand[(kh * 64 + 32 * mh + q * 4) * CSTR + ln];
      float* c1p = c0p + 16 * CSTR;
#pragma unroll
      for (int r = 0; r < 4; ++r) {
        c0p[r * CSTR] = acc0[r];
        c1p[r * CSTR] = acc1[r];
      }
    }
    __syncthreads();
    // ---- pointwise: reduce 4 K-quarters, gates, state update ----
    if (tid < 256) {
      float vi = b_i, vf = b_f, vo = b_o, vg = b_g;
#pragma unroll
      for (int p = 0; p < 4; ++p) {
        const float* cp = &cand[(p * 64 + pb) * CSTR];
        vi += cp[pj];
        vf += cp[4 + pj];
        vo += cp[8 + pj];
        vg += cp[12 + pj];
      }
      float ig = sigf(vi), fg = sigf(vf), og = sigf(vo), gg = tanhf_(vg);
      float cn = ig * gg + fg * c_reg;
      float hn = og * tanhf_(cn);
      if (t < Lb) { c_reg = cn; h_reg = hn; }  // freeze past sequence end
      hstage[tid] = f2bf(h_reg);
    }
    __syncthreads();
    if (tid < 64) {
      // publish h(t) into fresh step-slot t+1 (sc1 -> IF$, device-visible)
      u64 v = ((const u64*)hstage)[tid];
      u64* dst = (u64*)(hbuf + (size_t)(t + 1) * HSLOT + tid * 1024 + bid * 4);
      __hip_atomic_store(dst, v, __ATOMIC_RELAXED, __HIP_MEMORY_SCOPE_AGENT);
    }
    __syncthreads();  // drain publishes (vmcnt(0) before s_barrier)
    if (tid == 0)
      __hip_atomic_fetch_add(&cnt[t * CNT_STRIDE + (bid & 7) * 16], 1u,
                             __ATOMIC_RELAXED, __HIP_MEMORY_SCOPE_AGENT);
    // out-store AFTER arrive: off the inter-block critical path
    if (tid < 256)
      out[((size_t)t * BATCH + pb) * 1024 + bid * 4 + pj] = h_reg;
  }
}

extern "C" void kernel_launch(void* const* d_in, const int* in_sizes, int n_in,
                              void* d_out, int out_size, void* d_ws, size_t ws_size,
                              hipStream_t stream) {
  (void)in_sizes; (void)n_in; (void)out_size; (void)ws_size;
  const float* x = (const float*)d_in[0];
  const float* h0 = (const float*)d_in[1];
  const float* c0 = (const float*)d_in[2];
  const float* W = (const float*)d_in[3];
  const float* bias = (const float*)d_in[4];
  const int* L = (const int*)d_in[5];
  float* out = (float*)d_out;

  char* ws = (char*)d_ws;
  u32* cnt = (u32*)ws;
  u32* go = (u32*)(ws + GO_OFF);
  u16* xbf = (u16*)(ws + X_OFF);
  u16* hbuf = (u16*)(ws + H_OFF);

  hipFuncSetAttribute(reinterpret_cast<const void*>(lstm_persistent),
                      hipFuncAttributeMaxDynamicSharedMemorySize, 160 * 1024);
  hipMemsetAsync(ws, 0, X_OFF, stream);  // zero cnt + go
  hipLaunchKernelGGL(lstm_persistent, dim3(NBLK), dim3(THREADS), LDS_BYTES,
                     stream, x, h0, c0, W, bias, L, out, xbf, hbuf, cnt, go);
}